// Round 2
// baseline (1740.612 us; speedup 1.0000x reference)
//
#include <hip/hip_runtime.h>

typedef unsigned short u16;
typedef unsigned int   u32;

typedef __bf16 bf16x8 __attribute__((ext_vector_type(8)));
typedef float  f32x4  __attribute__((ext_vector_type(4)));

#define NB 1023   // nodes per tree
#define HH 1024   // hidden

__device__ __forceinline__ float b2f(u16 x) { return __uint_as_float(((u32)x) << 16); }
__device__ __forceinline__ u16 f2b(float f) {
    u32 u = __float_as_uint(f);
    u += 0x7fffu + ((u >> 16) & 1u);   // RTNE
    return (u16)(u >> 16);
}
__device__ __forceinline__ float fast_tanh(float x) {
    float cx = fminf(fmaxf(x, -12.f), 12.f);
    float e = __expf(2.f * cx);
    return __fdividef(e - 1.f, e + 1.f);
}
__device__ __forceinline__ void async_copy16(const void* gptr, void* lptr) {
    __builtin_amdgcn_global_load_lds((__attribute__((address_space(1))) void*)gptr,
                                     (__attribute__((address_space(3))) void*)lptr,
                                     16, 0, 0);
}
// read element idx of a float tensor that is either f32 or bf16 in memory
__device__ __forceinline__ u16 loadAsBf16(const void* p, size_t idx, int isf32) {
    if (isf32) return f2b(((const float*)p)[idx]);
    return ((const u16*)p)[idx];
}

// ---------------- dtype detection: f32 mantissa low-halves have random exponents
__global__ void detect_dtype(const u32* __restrict__ w, u32* __restrict__ flag) {
    __shared__ int cnt;
    const int tid = threadIdx.x;
    if (tid == 0) cnt = 0;
    __syncthreads();
    u32 v = w[tid];
    u32 lo = v & 0xFFFFu;
    u32 e = (lo >> 7) & 0xFFu;
    int insane = (lo != 0u) && (e < 60u || e > 140u);
    if (insane) atomicAdd(&cnt, 1);
    __syncthreads();
    if (tid == 0) *flag = (cnt >= 64) ? 1u : 0u;
}

// ---------------- small tensor convert to canonical bf16
__global__ void conv_small(const void* __restrict__ src, u16* __restrict__ dst,
                           int n, const u32* __restrict__ flagp) {
    const int isf32 = (int)flagp[0];
    const int i = blockIdx.x * 256 + threadIdx.x;
    if (i < n) dst[i] = loadAsBf16(src, i, isf32);
}

// ---------------- weight transpose + K-pad:  W[K][Nw] -> Wt[Nw][Kpad], zeros for k>=K
__global__ void transpose_pad(const void* __restrict__ W, u16* __restrict__ Wt,
                              int K, int Nw, int Kpad, const u32* __restrict__ flagp)
{
    __shared__ u16 tile[32][33];
    const int isf32 = (int)flagp[0];
    const int bx = blockIdx.x, by = blockIdx.y;
    const int tx = threadIdx.x, ty = threadIdx.y;   // block (32,8)
    #pragma unroll
    for (int i = 0; i < 4; ++i) {
        const int k = by*32 + ty + i*8;
        const int n = bx*32 + tx;
        u16 v = 0;
        if (k < K) v = loadAsBf16(W, (size_t)k * Nw + n, isf32);
        tile[ty + i*8][tx] = v;
    }
    __syncthreads();
    #pragma unroll
    for (int i = 0; i < 4; ++i) {
        const int n = bx*32 + ty + i*8;
        const int k = by*32 + tx;
        Wt[(size_t)n * Kpad + k] = tile[tx][ty + i*8];
    }
}

// ---------------- gathers (build zero-padded ctx rows) ----------------
// leaf ctx row (Kpad=1088): [word_emb(1024) | onehot(3) | syn(pos)(50) | 0(11)]
__global__ __launch_bounds__(256)
void leaf_gather(const int* __restrict__ x, const int* __restrict__ cue,
                 const int* __restrict__ pos, const void* __restrict__ wemb,
                 const u16* __restrict__ semb, u16* __restrict__ ctx,
                 const u32* __restrict__ flagp)
{
    const int isf32 = (int)flagp[0];
    const int m = blockIdx.x;           // 0..16383
    const int b = m >> 9, i = m & 511;
    const int node = 511 + i;
    const int s  = x[b*NB + node];
    const int cv = cue[b*NB + node];
    const int p  = pos[b*512 + i];
    u16* row = ctx + (size_t)m * 1088;
    u32* row32 = (u32*)row;
    const u16* sr = semb + p * 50;
    const int tid = threadIdx.x;
    if (isf32) {
        const float2* wrf = ((const float2*)wemb) + (size_t)s * 512;
        for (int c = tid; c < 512; c += 256) {
            float2 t = wrf[c];
            row32[c] = (u32)f2b(t.x) | ((u32)f2b(t.y) << 16);
        }
    } else {
        const u32* wr = ((const u32*)wemb) + (size_t)s * 512;
        for (int c = tid; c < 512; c += 256) row32[c] = wr[c];
    }
    if (tid < 64) {
        const int c = tid;              // elem 1024+c
        u16 v;
        if (c < 3)       v = (c == cv) ? (u16)0x3F80 : (u16)0;
        else if (c < 53) v = sr[c - 3];
        else             v = 0;
        row[1024 + c] = v;
    }
}

// up ctx row (Kpad=2112): [syn(x[node])(50) | up[l](1024) | up[r](1024) | 0(14)]
__global__ __launch_bounds__(256)
void up_gather(const int* __restrict__ x, const u16* __restrict__ semb,
               const u16* __restrict__ up, u16* __restrict__ ctx,
               int M, int first, int lognn)
{
    const int m = blockIdx.x;
    u32* row32 = (u32*)(ctx + (size_t)m * 2112);
    const int tid = threadIdx.x;
    if (m >= M) { for (int c = tid; c < 1056; c += 256) row32[c] = 0; return; }
    const int b = m >> lognn, i = m & ((1 << lognn) - 1);
    const int node = first + i;
    const int s = x[b*NB + node];
    const u32* sr = (const u32*)(semb + s * 50);
    const u32* ul = (const u32*)(up + ((size_t)(b*NB + 2*node + 1) << 10));
    const u32* ur = (const u32*)(up + ((size_t)(b*NB + 2*node + 2) << 10));
    if (tid < 25) row32[tid] = sr[tid];
    for (int c = tid; c < 512; c += 256) row32[25 + c]  = ul[c];
    for (int c = tid; c < 512; c += 256) row32[537 + c] = ur[c];
    if (tid < 7) row32[1049 + tid] = 0;
}

// root ctx row (Kpad=1088): [up[0](1024) | syn(x[0])(50) | 0(14)]
__global__ __launch_bounds__(256)
void root_gather(const int* __restrict__ x, const u16* __restrict__ semb,
                 const u16* __restrict__ up, u16* __restrict__ ctx)
{
    const int m = blockIdx.x;           // 0..127
    u32* row32 = (u32*)(ctx + (size_t)m * 1088);
    const int tid = threadIdx.x;
    if (m >= 32) { for (int c = tid; c < 544; c += 256) row32[c] = 0; return; }
    const int s = x[m*NB];
    const u32* u0 = (const u32*)(up + ((size_t)(m*NB) << 10));
    const u32* sr = (const u32*)(semb + s * 50);
    for (int c = tid; c < 512; c += 256) row32[c] = u0[c];
    if (tid < 25) row32[512 + tid] = sr[tid];
    if (tid < 7)  row32[537 + tid] = 0;
}

// down ctx row (Kpad=2176): [consL(50) | consR(50) | down[node](1024) | up[node](1024) | 0(28)]
__global__ __launch_bounds__(256)
void down_gather(const int* __restrict__ x, const int* __restrict__ pos,
                 const u16* __restrict__ semb, const u16* __restrict__ up,
                 const u16* __restrict__ down, u16* __restrict__ ctx,
                 int M, int first, int lognn, int leafLvl)
{
    const int m = blockIdx.x;
    u32* row32 = (u32*)(ctx + (size_t)m * 2176);
    const int tid = threadIdx.x;
    if (m >= M) { for (int c = tid; c < 1088; c += 256) row32[c] = 0; return; }
    const int b = m >> lognn, i = m & ((1 << lognn) - 1);
    const int node = first + i;
    const int l = 2*node + 1, r = l + 1;
    int sli, sri;
    if (leafLvl) { sli = pos[b*512 + (l - 511)]; sri = pos[b*512 + (r - 511)]; }
    else         { sli = x[b*NB + l];            sri = x[b*NB + r]; }
    const u32* sl = (const u32*)(semb + sli * 50);
    const u32* sr = (const u32*)(semb + sri * 50);
    const u32* dn = (const u32*)(down + ((size_t)(b*NB + node) << 10));
    const u32* un = (const u32*)(up   + ((size_t)(b*NB + node) << 10));
    if (tid < 25)      row32[tid] = sl[tid];
    else if (tid < 50) row32[tid] = sr[tid - 25];
    for (int c = tid; c < 512; c += 256) row32[50 + c]  = dn[c];
    for (int c = tid; c < 512; c += 256) row32[562 + c] = un[c];
    if (tid < 14) row32[1074 + tid] = 0;
}

// ---------------- GEMM: A[Mpad x Kpad] * Bt[N x Kpad]^T + bias, mode epilogue ----
// mode 0: store (no tanh) at node(gm); mode 1: tanh, node(gm); mode 2: tanh, child split (N=2048)
__global__ __launch_bounds__(256)
void gemm_kernel(const u16* __restrict__ A, const u16* __restrict__ Bt,
                 const u16* __restrict__ bias, u16* __restrict__ dst,
                 int M, int Kpad, int mode, int nodeBase, int lognn)
{
    __shared__ __align__(16) u16 As[128*32];
    __shared__ __align__(16) u16 Bs[128*32];
    const int tid  = threadIdx.x;
    const int wave = tid >> 6;
    const int lane = tid & 63;
    const int bm = blockIdx.y << 7;
    const int bn = blockIdx.x << 7;
    const int wm = (wave & 1) << 6;
    const int wn = (wave >> 1) << 6;
    const int quad = lane >> 4;
    const int l16  = lane & 15;
    const int srow = lane >> 2;
    const int scol = (lane & 3) << 3;

    const u16* gA0 = A  + (size_t)(bm + wave*16 + srow) * Kpad + scol;
    const u16* gA1 = gA0 + (size_t)64 * Kpad;
    const u16* gB0 = Bt + (size_t)(bn + wave*16 + srow) * Kpad + scol;
    const u16* gB1 = gB0 + (size_t)64 * Kpad;
    u16* lA0 = &As[wave * 512];
    u16* lA1 = &As[(wave + 4) * 512];
    u16* lB0 = &Bs[wave * 512];
    u16* lB1 = &Bs[(wave + 4) * 512];

    const u16* pa[4]; const u16* pb[4];
    #pragma unroll
    for (int i = 0; i < 4; ++i) pa[i] = &As[(wm + i*16 + l16) * 32 + quad*8];
    #pragma unroll
    for (int j = 0; j < 4; ++j) pb[j] = &Bs[(wn + j*16 + l16) * 32 + quad*8];

    f32x4 zero4 = {0.f, 0.f, 0.f, 0.f};
    f32x4 acc[4][4];
    #pragma unroll
    for (int i = 0; i < 4; ++i)
        #pragma unroll
        for (int j = 0; j < 4; ++j) acc[i][j] = zero4;

    for (int k0 = 0; k0 < Kpad; k0 += 32) {
        async_copy16(gA0 + k0, lA0);
        async_copy16(gA1 + k0, lA1);
        async_copy16(gB0 + k0, lB0);
        async_copy16(gB1 + k0, lB1);
        __syncthreads();
        bf16x8 a[4], b[4];
        #pragma unroll
        for (int i = 0; i < 4; ++i) a[i] = *(const bf16x8*)pa[i];
        #pragma unroll
        for (int j = 0; j < 4; ++j) b[j] = *(const bf16x8*)pb[j];
        #pragma unroll
        for (int i = 0; i < 4; ++i)
            #pragma unroll
            for (int j = 0; j < 4; ++j)
                acc[i][j] = __builtin_amdgcn_mfma_f32_16x16x32_bf16(a[i], b[j], acc[i][j], 0, 0, 0);
        __syncthreads();
    }

    const int mask = (1 << lognn) - 1;
    #pragma unroll
    for (int i = 0; i < 4; ++i) {
        #pragma unroll
        for (int j = 0; j < 4; ++j) {
            const int gn = bn + wn + j*16 + l16;
            const float bv = b2f(bias[gn]);
            #pragma unroll
            for (int r = 0; r < 4; ++r) {
                const int gm = bm + wm + i*16 + quad*4 + r;
                if (gm < M) {
                    float v = acc[i][j][r] + bv;
                    if (mode != 0) v = fast_tanh(v);
                    const int b_ = gm >> lognn;
                    const int ii = gm & mask;
                    const int node = nodeBase + ii;
                    size_t addr;
                    if (mode == 2) {
                        const int child = 2*node + 1 + (gn >> 10);
                        addr = (((size_t)(b_*NB + child)) << 10) + (gn & 1023);
                    } else {
                        addr = (((size_t)(b_*NB + node)) << 10) + gn;
                    }
                    dst[addr] = f2b(v);
                }
            }
        }
    }
}

// ---------------- classifier: out[b,n,c] = tanh([down|up] . clfW[:,c] + clfb[c]) ----
__global__ __launch_bounds__(256)
void classifier_kernel(const u16* __restrict__ down, const u16* __restrict__ up,
                       const u16* __restrict__ clfW, const u16* __restrict__ clfb,
                       void* __restrict__ outp, const u32* __restrict__ flagp)
{
    __shared__ float wls[3][2048];
    const int isf32 = (int)flagp[0];
    const int tid = threadIdx.x;
    for (int idx = tid; idx < 6144; idx += 256) {
        const int c = idx >> 11, k = idx & 2047;
        wls[c][k] = b2f(clfW[k*3 + c]);
    }
    __syncthreads();
    const int wave = tid >> 6, lane = tid & 63;
    const float b0 = b2f(clfb[0]), b1 = b2f(clfb[1]), b2v = b2f(clfb[2]);
    const int base = blockIdx.x * 32;
    for (int rr = 0; rr < 8; ++rr) {
        const int row = base + rr*4 + wave;     // row = b*NB + node
        const u32* dn = (const u32*)(down + ((size_t)row << 10));
        const u32* un = (const u32*)(up   + ((size_t)row << 10));
        float a0 = 0.f, a1 = 0.f, a2 = 0.f;
        #pragma unroll
        for (int t = 0; t < 8; ++t) {
            const int j = t*64 + lane;
            const u32 dp = dn[j], uu = un[j];
            const int k = j*2;
            const float d0 = __uint_as_float(dp << 16);
            const float d1 = __uint_as_float(dp & 0xffff0000u);
            const float u0 = __uint_as_float(uu << 16);
            const float u1 = __uint_as_float(uu & 0xffff0000u);
            a0 += d0*wls[0][k] + d1*wls[0][k+1] + u0*wls[0][1024+k] + u1*wls[0][1025+k];
            a1 += d0*wls[1][k] + d1*wls[1][k+1] + u0*wls[1][1024+k] + u1*wls[1][1025+k];
            a2 += d0*wls[2][k] + d1*wls[2][k+1] + u0*wls[2][1024+k] + u1*wls[2][1025+k];
        }
        #pragma unroll
        for (int off = 32; off; off >>= 1) {
            a0 += __shfl_down(a0, off);
            a1 += __shfl_down(a1, off);
            a2 += __shfl_down(a2, off);
        }
        if (lane == 0) {
            const float v0 = fast_tanh(a0 + b0);
            const float v1 = fast_tanh(a1 + b1);
            const float v2 = fast_tanh(a2 + b2v);
            if (isf32) {
                float* o = (float*)outp + (size_t)row * 3;
                o[0] = v0; o[1] = v1; o[2] = v2;
            } else {
                u16* o = (u16*)outp + (size_t)row * 3;
                o[0] = f2b(v0); o[1] = f2b(v1); o[2] = f2b(v2);
            }
        }
    }
}

extern "C" void kernel_launch(void* const* d_in, const int* in_sizes, int n_in,
                              void* d_out, int out_size, void* d_ws, size_t ws_size,
                              hipStream_t stream)
{
    (void)in_sizes; (void)n_in; (void)out_size; (void)ws_size;
    const int* x    = (const int*)d_in[0];
    const int* cue  = (const int*)d_in[2];
    const int* pos  = (const int*)d_in[4];
    const void* wemb  = d_in[6];
    const void* semb  = d_in[7];
    const void* leafW = d_in[8];
    const void* leafb = d_in[9];
    const void* compW = d_in[10];
    const void* compb = d_in[11];
    const void* grevW = d_in[12];
    const void* grevb = d_in[13];
    const void* decW  = d_in[14];
    const void* decb  = d_in[15];
    const void* clfW  = d_in[16];
    const void* clfb  = d_in[17];

    char* ws = (char*)d_ws;
    u16* up_buf   = (u16*)(ws + 0);            // 32*1023*1024*2 = 67043328
    u16* down_buf = (u16*)(ws + 67043328);     // same
    u16* ctx      = (u16*)(ws + 134086656);    // 35651584 B
    u16* leafWt   = (u16*)(ws + 169738240);    // 1024x1088
    u16* compWt   = (u16*)(ws + 171966464);    // 1024x2112
    u16* grevWt   = (u16*)(ws + 176291840);    // 1024x1088
    u16* decWt    = (u16*)(ws + 178520064);    // 2048x2176  (end 187432960)
    u16* sembC    = (u16*)(ws + 187432960);    // 128x50
    u16* leafbC   = (u16*)(ws + 187445760);    // 1024
    u16* compbC   = (u16*)(ws + 187447808);    // 1024
    u16* grevbC   = (u16*)(ws + 187449856);    // 1024
    u16* decbC    = (u16*)(ws + 187451904);    // 2048
    u16* clfbC    = (u16*)(ws + 187456000);    // 3 (pad)
    u16* clfWC    = (u16*)(ws + 187456016);    // 6144
    u32* flag     = (u32*)(ws + 187468304);

    detect_dtype<<<1, 256, 0, stream>>>((const u32*)wemb, flag);

    conv_small<<<25, 256, 0, stream>>>(semb,  sembC,  6400, flag);
    conv_small<<<4,  256, 0, stream>>>(leafb, leafbC, 1024, flag);
    conv_small<<<4,  256, 0, stream>>>(compb, compbC, 1024, flag);
    conv_small<<<4,  256, 0, stream>>>(grevb, grevbC, 1024, flag);
    conv_small<<<8,  256, 0, stream>>>(decb,  decbC,  2048, flag);
    conv_small<<<1,  256, 0, stream>>>(clfb,  clfbC,  3,    flag);
    conv_small<<<24, 256, 0, stream>>>(clfW,  clfWC,  6144, flag);

    dim3 tb(32, 8);
    transpose_pad<<<dim3(32, 34), tb, 0, stream>>>(leafW, leafWt, 1077, 1024, 1088, flag);
    transpose_pad<<<dim3(32, 66), tb, 0, stream>>>(compW, compWt, 2098, 1024, 2112, flag);
    transpose_pad<<<dim3(32, 34), tb, 0, stream>>>(grevW, grevWt, 1074, 1024, 1088, flag);
    transpose_pad<<<dim3(64, 68), tb, 0, stream>>>(decW,  decWt,  2148, 2048, 2176, flag);

    // leaves -> up[511..1022]
    leaf_gather<<<16384, 256, 0, stream>>>(x, cue, pos, wemb, sembC, ctx, flag);
    gemm_kernel<<<dim3(8, 128), 256, 0, stream>>>(ctx, leafWt, leafbC, up_buf,
                                                  16384, 1088, 0, 511, 9);
    // upward
    for (int lvl = 8; lvl >= 0; --lvl) {
        const int M = 32 << lvl;
        const int Mpad = M < 128 ? 128 : M;
        const int first = (1 << lvl) - 1;
        up_gather<<<Mpad, 256, 0, stream>>>(x, sembC, up_buf, ctx, M, first, lvl);
        gemm_kernel<<<dim3(8, Mpad >> 7), 256, 0, stream>>>(ctx, compWt, compbC, up_buf,
                                                            M, 2112, 1, first, lvl);
    }
    // root -> down[0]
    root_gather<<<128, 256, 0, stream>>>(x, sembC, up_buf, ctx);
    gemm_kernel<<<dim3(8, 1), 256, 0, stream>>>(ctx, grevWt, grevbC, down_buf,
                                                32, 1088, 1, 0, 0);
    // downward
    for (int lvl = 0; lvl <= 8; ++lvl) {
        const int M = 32 << lvl;
        const int Mpad = M < 128 ? 128 : M;
        const int first = (1 << lvl) - 1;
        down_gather<<<Mpad, 256, 0, stream>>>(x, pos, sembC, up_buf, down_buf, ctx,
                                              M, first, lvl, lvl == 8 ? 1 : 0);
        gemm_kernel<<<dim3(16, Mpad >> 7), 256, 0, stream>>>(ctx, decWt, decbC, down_buf,
                                                             M, 2176, 2, first, lvl);
    }
    // classifier
    classifier_kernel<<<1023, 256, 0, stream>>>(down_buf, up_buf, clfWC, clfbC, d_out, flag);
}

// Round 3
// 1420.309 us; speedup vs baseline: 1.2255x; 1.2255x over previous
//
#include <hip/hip_runtime.h>

typedef unsigned short u16;
typedef unsigned int   u32;

typedef __bf16 bf16x8 __attribute__((ext_vector_type(8)));
typedef float  f32x4  __attribute__((ext_vector_type(4)));

#define NB 1023   // nodes per tree
#define HH 1024   // hidden

__device__ __forceinline__ float b2f(u16 x) { return __uint_as_float(((u32)x) << 16); }
__device__ __forceinline__ u16 f2b(float f) {
    u32 u = __float_as_uint(f);
    u += 0x7fffu + ((u >> 16) & 1u);   // RTNE
    return (u16)(u >> 16);
}
__device__ __forceinline__ float fast_tanh(float x) {
    float cx = fminf(fmaxf(x, -12.f), 12.f);
    float e = __expf(2.f * cx);
    return __fdividef(e - 1.f, e + 1.f);
}
__device__ __forceinline__ void async_copy16(const void* gptr, void* lptr) {
    __builtin_amdgcn_global_load_lds((__attribute__((address_space(1))) void*)gptr,
                                     (__attribute__((address_space(3))) void*)lptr,
                                     16, 0, 0);
}
__device__ __forceinline__ u16 loadAsBf16(const void* p, size_t idx, int isf32) {
    if (isf32) return f2b(((const float*)p)[idx]);
    return ((const u16*)p)[idx];
}

// ---------------- dtype detection: f32 mantissa low-halves have random exponents
__global__ void detect_dtype(const u32* __restrict__ w, u32* __restrict__ flag) {
    __shared__ int cnt;
    const int tid = threadIdx.x;
    if (tid == 0) cnt = 0;
    __syncthreads();
    u32 v = w[tid];
    u32 lo = v & 0xFFFFu;
    u32 e = (lo >> 7) & 0xFFu;
    int insane = (lo != 0u) && (e < 60u || e > 140u);
    if (insane) atomicAdd(&cnt, 1);
    __syncthreads();
    if (tid == 0) *flag = (cnt >= 64) ? 1u : 0u;
}

// ---------------- small tensor convert to canonical bf16
__global__ void conv_small(const void* __restrict__ src, u16* __restrict__ dst,
                           int n, const u32* __restrict__ flagp) {
    const int isf32 = (int)flagp[0];
    const int i = blockIdx.x * 256 + threadIdx.x;
    if (i < n) dst[i] = loadAsBf16(src, i, isf32);
}

// ---------------- syn emb table, padded 50 -> 64 per row
__global__ void conv_sembP(const void* __restrict__ semb, u16* __restrict__ sembP,
                           const u32* __restrict__ flagp) {
    const int isf32 = (int)flagp[0];
    const int i = blockIdx.x * 256 + threadIdx.x;   // 8192 = 128*64
    const int s = i >> 6, c = i & 63;
    sembP[i] = (c < 50) ? loadAsBf16(semb, s * 50 + c, isf32) : (u16)0;
}

// ---------------- weight transpose, segment-remapped K-pad:
// W[Korig][Nw] -> Wt[Nw][Kpad]; padded k in seg i maps to orig k, else 0
__global__ void transpose_pad(const void* __restrict__ W, u16* __restrict__ Wt,
                              int Nw, int Kpad, const u32* __restrict__ flagp,
                              int4 ps, int4 os, int4 ln)
{
    __shared__ u16 tile[32][33];
    const int isf32 = (int)flagp[0];
    const int bx = blockIdx.x, by = blockIdx.y;
    const int tx = threadIdx.x, ty = threadIdx.y;   // block (32,8)
    #pragma unroll
    for (int i = 0; i < 4; ++i) {
        const int kp = by*32 + ty + i*8;
        const int n = bx*32 + tx;
        int ko = -1;
        if      (kp >= ps.x && kp < ps.x + ln.x) ko = os.x + (kp - ps.x);
        else if (kp >= ps.y && kp < ps.y + ln.y) ko = os.y + (kp - ps.y);
        else if (kp >= ps.z && kp < ps.z + ln.z) ko = os.z + (kp - ps.z);
        else if (kp >= ps.w && kp < ps.w + ln.w) ko = os.w + (kp - ps.w);
        u16 v = 0;
        if (ko >= 0) v = loadAsBf16(W, (size_t)ko * Nw + n, isf32);
        tile[ty + i*8][tx] = v;
    }
    __syncthreads();
    #pragma unroll
    for (int i = 0; i < 4; ++i) {
        const int n = bx*32 + ty + i*8;
        const int kp = by*32 + tx;
        Wt[(size_t)n * Kpad + kp] = tile[tx][ty + i*8];
    }
}

// ---------------- leaf ctx (Kpad=1088): [word(1024) | onehot(3) | syn(pos)(50) | 0(11)]
__global__ __launch_bounds__(256)
void leaf_gather(const int* __restrict__ x, const int* __restrict__ cue,
                 const int* __restrict__ pos, const void* __restrict__ wemb,
                 const u16* __restrict__ sembP, u16* __restrict__ ctx,
                 const u32* __restrict__ flagp)
{
    const int isf32 = (int)flagp[0];
    const int m = blockIdx.x;           // 0..16383
    const int b = m >> 9, i = m & 511;
    const int node = 511 + i;
    const int s  = x[b*NB + node];
    const int cv = cue[b*NB + node];
    const int p  = pos[b*512 + i];
    u16* row = ctx + (size_t)m * 1088;
    u32* row32 = (u32*)row;
    const u16* sr = sembP + p * 64;
    const int tid = threadIdx.x;
    if (isf32) {
        const float2* wrf = ((const float2*)wemb) + (size_t)s * 512;
        for (int c = tid; c < 512; c += 256) {
            float2 t = wrf[c];
            row32[c] = (u32)f2b(t.x) | ((u32)f2b(t.y) << 16);
        }
    } else {
        const u32* wr = ((const u32*)wemb) + (size_t)s * 512;
        for (int c = tid; c < 512; c += 256) row32[c] = wr[c];
    }
    if (tid < 64) {
        const int c = tid;              // elem 1024+c
        u16 v;
        if (c < 3)       v = (c == cv) ? (u16)0x3F80 : (u16)0;
        else if (c < 53) v = sr[c - 3];
        else             v = 0;
        row[1024 + c] = v;
    }
}

// ---------------- fused gather+GEMM ----------------
// C[M x N] = A[M x Kpad] * Bt[N x Kpad]^T + bias; A staged on the fly.
// AKIND 0: A = actx rows (leaf).             Kpad variable.
// AKIND 1: up level:   [semb(s)|up_l|up_r]   Kpad=2112 (64+1024+1024)
// AKIND 2: root:       [up0|semb(s)]         Kpad=1088 (1024+64)
// AKIND 3: down level: [sL|sR|down_n|up_n]   Kpad=2176 (64+64+1024+1024)
// MODE 0: store raw; 1: tanh; 2: tanh + child split (N=2048)
template<int AKIND, int MODE>
__global__ __launch_bounds__(256)
void gemm_fused(const u16* __restrict__ Bt, const u16* __restrict__ bias,
                u16* __restrict__ dst, int M, int Kpad, int nodeBase, int lognn,
                int leafLvl,
                const u16* __restrict__ actx,
                const int* __restrict__ x, const int* __restrict__ pos,
                const u16* __restrict__ sembP,
                const u16* __restrict__ upB, const u16* __restrict__ downB)
{
    __shared__ __align__(16) u16 As[128*32];
    __shared__ __align__(16) u16 Bs[128*32];
    const int tid  = threadIdx.x;
    const int wave = tid >> 6;
    const int lane = tid & 63;
    const int bm = blockIdx.y << 7;
    const int bn = blockIdx.x << 7;
    const int wm = (wave & 1) << 6;
    const int wn = (wave >> 1) << 6;
    const int quad = lane >> 4;
    const int l16  = lane & 15;
    const int srow = lane >> 2;
    const int scol = (lane & 3) << 3;
    const int mask = (1 << lognn) - 1;

    // per-lane staging source pointers for its two A rows (mrow, mrow+64)
    const u16* p0[2]; const u16* p1[2]; const u16* p2[2]; const u16* p3[2];
    #pragma unroll
    for (int h = 0; h < 2; ++h) {
        const int mrow = bm + wave*16 + srow + h*64;
        // rows >= M stage harmless in-bounds data; their C rows are discarded
        const int mr = (mrow < M) ? mrow : 0;
        if (AKIND == 0) {
            p0[h] = actx + (size_t)mr * Kpad + scol;
        } else if (AKIND == 1) {
            const int b_ = mr >> lognn, ii = mr & mask;
            const int node = nodeBase + ii;
            const int s = x[b_*NB + node];
            p0[h] = sembP + s*64 + scol;
            p1[h] = upB + (((size_t)(b_*NB + 2*node + 1)) << 10) + scol;
            p2[h] = upB + (((size_t)(b_*NB + 2*node + 2)) << 10) + scol;
        } else if (AKIND == 2) {
            p0[h] = upB + (((size_t)(mr*NB)) << 10) + scol;
            p1[h] = sembP + x[mr*NB]*64 + scol;
        } else {
            const int b_ = mr >> lognn, ii = mr & mask;
            const int node = nodeBase + ii;
            const int l = 2*node + 1, r = l + 1;
            int sli, sri;
            if (leafLvl) { sli = pos[b_*512 + (l-511)]; sri = pos[b_*512 + (r-511)]; }
            else         { sli = x[b_*NB + l]; sri = x[b_*NB + r]; }
            p0[h] = sembP + sli*64 + scol;
            p1[h] = sembP + sri*64 + scol;
            p2[h] = downB + (((size_t)(b_*NB + node)) << 10) + scol;
            p3[h] = upB   + (((size_t)(b_*NB + node)) << 10) + scol;
        }
    }

    const u16* gB0 = Bt + (size_t)(bn + wave*16 + srow) * Kpad + scol;
    const u16* gB1 = gB0 + (size_t)64 * Kpad;
    u16* lA0 = &As[wave * 512];
    u16* lA1 = &As[(wave + 4) * 512];
    u16* lB0 = &Bs[wave * 512];
    u16* lB1 = &Bs[(wave + 4) * 512];

    const u16* pa[4]; const u16* pb[4];
    #pragma unroll
    for (int i = 0; i < 4; ++i) pa[i] = &As[(wm + i*16 + l16) * 32 + quad*8];
    #pragma unroll
    for (int j = 0; j < 4; ++j) pb[j] = &Bs[(wn + j*16 + l16) * 32 + quad*8];

    f32x4 zero4 = {0.f, 0.f, 0.f, 0.f};
    f32x4 acc[4][4];
    #pragma unroll
    for (int i = 0; i < 4; ++i)
        #pragma unroll
        for (int j = 0; j < 4; ++j) acc[i][j] = zero4;

    auto kstep = [&](const u16* sA0, const u16* sA1, int k0) {
        async_copy16(sA0, lA0);
        async_copy16(sA1, lA1);
        async_copy16(gB0 + k0, lB0);
        async_copy16(gB1 + k0, lB1);
        __syncthreads();
        bf16x8 a[4], b[4];
        #pragma unroll
        for (int i = 0; i < 4; ++i) a[i] = *(const bf16x8*)pa[i];
        #pragma unroll
        for (int j = 0; j < 4; ++j) b[j] = *(const bf16x8*)pb[j];
        #pragma unroll
        for (int i = 0; i < 4; ++i)
            #pragma unroll
            for (int j = 0; j < 4; ++j)
                acc[i][j] = __builtin_amdgcn_mfma_f32_16x16x32_bf16(a[i], b[j], acc[i][j], 0, 0, 0);
        __syncthreads();
    };

    if (AKIND == 0) {
        for (int k0 = 0; k0 < Kpad; k0 += 32) kstep(p0[0] + k0, p0[1] + k0, k0);
    } else if (AKIND == 1) {
        for (int k0 = 0;    k0 < 64;   k0 += 32) kstep(p0[0] + k0,        p0[1] + k0,        k0);
        for (int k0 = 64;   k0 < 1088; k0 += 32) kstep(p1[0] + (k0-64),   p1[1] + (k0-64),   k0);
        for (int k0 = 1088; k0 < 2112; k0 += 32) kstep(p2[0] + (k0-1088), p2[1] + (k0-1088), k0);
    } else if (AKIND == 2) {
        for (int k0 = 0;    k0 < 1024; k0 += 32) kstep(p0[0] + k0,        p0[1] + k0,        k0);
        for (int k0 = 1024; k0 < 1088; k0 += 32) kstep(p1[0] + (k0-1024), p1[1] + (k0-1024), k0);
    } else {
        for (int k0 = 0;    k0 < 64;   k0 += 32) kstep(p0[0] + k0,        p0[1] + k0,        k0);
        for (int k0 = 64;   k0 < 128;  k0 += 32) kstep(p1[0] + (k0-64),   p1[1] + (k0-64),   k0);
        for (int k0 = 128;  k0 < 1152; k0 += 32) kstep(p2[0] + (k0-128),  p2[1] + (k0-128),  k0);
        for (int k0 = 1152; k0 < 2176; k0 += 32) kstep(p3[0] + (k0-1152), p3[1] + (k0-1152), k0);
    }

    #pragma unroll
    for (int i = 0; i < 4; ++i) {
        #pragma unroll
        for (int j = 0; j < 4; ++j) {
            const int gn = bn + wn + j*16 + l16;
            const float bv = b2f(bias[gn]);
            #pragma unroll
            for (int r = 0; r < 4; ++r) {
                const int gm = bm + wm + i*16 + quad*4 + r;
                if (gm < M) {
                    float v = acc[i][j][r] + bv;
                    if (MODE != 0) v = fast_tanh(v);
                    const int b_ = gm >> lognn;
                    const int ii = gm & mask;
                    const int node = nodeBase + ii;
                    size_t addr;
                    if (MODE == 2) {
                        const int child = 2*node + 1 + (gn >> 10);
                        addr = (((size_t)(b_*NB + child)) << 10) + (gn & 1023);
                    } else {
                        addr = (((size_t)(b_*NB + node)) << 10) + gn;
                    }
                    dst[addr] = f2b(v);
                }
            }
        }
    }
}

// ---------------- classifier: out[b,n,c] = tanh([down|up] . clfW[:,c] + clfb[c]) ----
__global__ __launch_bounds__(256)
void classifier_kernel(const u16* __restrict__ down, const u16* __restrict__ up,
                       const u16* __restrict__ clfW, const u16* __restrict__ clfb,
                       void* __restrict__ outp, const u32* __restrict__ flagp)
{
    __shared__ float wls[3][2048];
    const int isf32 = (int)flagp[0];
    const int tid = threadIdx.x;
    for (int idx = tid; idx < 6144; idx += 256) {
        const int c = idx >> 11, k = idx & 2047;
        wls[c][k] = b2f(clfW[k*3 + c]);
    }
    __syncthreads();
    const int wave = tid >> 6, lane = tid & 63;
    const float b0 = b2f(clfb[0]), b1 = b2f(clfb[1]), b2v = b2f(clfb[2]);
    const int base = blockIdx.x * 32;
    for (int rr = 0; rr < 8; ++rr) {
        const int row = base + rr*4 + wave;     // row = b*NB + node
        const u32* dn = (const u32*)(down + ((size_t)row << 10));
        const u32* un = (const u32*)(up   + ((size_t)row << 10));
        float a0 = 0.f, a1 = 0.f, a2 = 0.f;
        #pragma unroll
        for (int t = 0; t < 8; ++t) {
            const int j = t*64 + lane;
            const u32 dp = dn[j], uu = un[j];
            const int k = j*2;
            const float d0 = __uint_as_float(dp << 16);
            const float d1 = __uint_as_float(dp & 0xffff0000u);
            const float u0 = __uint_as_float(uu << 16);
            const float u1 = __uint_as_float(uu & 0xffff0000u);
            a0 += d0*wls[0][k] + d1*wls[0][k+1] + u0*wls[0][1024+k] + u1*wls[0][1025+k];
            a1 += d0*wls[1][k] + d1*wls[1][k+1] + u0*wls[1][1024+k] + u1*wls[1][1025+k];
            a2 += d0*wls[2][k] + d1*wls[2][k+1] + u0*wls[2][1024+k] + u1*wls[2][1025+k];
        }
        #pragma unroll
        for (int off = 32; off; off >>= 1) {
            a0 += __shfl_down(a0, off);
            a1 += __shfl_down(a1, off);
            a2 += __shfl_down(a2, off);
        }
        if (lane == 0) {
            const float v0 = fast_tanh(a0 + b0);
            const float v1 = fast_tanh(a1 + b1);
            const float v2 = fast_tanh(a2 + b2v);
            if (isf32) {
                float* o = (float*)outp + (size_t)row * 3;
                o[0] = v0; o[1] = v1; o[2] = v2;
            } else {
                u16* o = (u16*)outp + (size_t)row * 3;
                o[0] = f2b(v0); o[1] = f2b(v1); o[2] = f2b(v2);
            }
        }
    }
}

extern "C" void kernel_launch(void* const* d_in, const int* in_sizes, int n_in,
                              void* d_out, int out_size, void* d_ws, size_t ws_size,
                              hipStream_t stream)
{
    (void)in_sizes; (void)n_in; (void)out_size; (void)ws_size;
    const int* x    = (const int*)d_in[0];
    const int* cue  = (const int*)d_in[2];
    const int* pos  = (const int*)d_in[4];
    const void* wemb  = d_in[6];
    const void* semb  = d_in[7];
    const void* leafW = d_in[8];
    const void* leafb = d_in[9];
    const void* compW = d_in[10];
    const void* compb = d_in[11];
    const void* grevW = d_in[12];
    const void* grevb = d_in[13];
    const void* decW  = d_in[14];
    const void* decb  = d_in[15];
    const void* clfW  = d_in[16];
    const void* clfb  = d_in[17];

    char* ws = (char*)d_ws;
    u16* up_buf   = (u16*)(ws + 0);            // 67043328
    u16* down_buf = (u16*)(ws + 67043328);     // 67043328
    u16* ctx      = (u16*)(ws + 134086656);    // 35651584 (leaf only)
    u16* leafWt   = (u16*)(ws + 169738240);    // 1024x1088
    u16* compWt   = (u16*)(ws + 171966464);    // 1024x2112
    u16* grevWt   = (u16*)(ws + 176291840);    // 1024x1088
    u16* decWt    = (u16*)(ws + 178520064);    // 2048x2176
    u16* sembP    = (u16*)(ws + 187432960);    // 128x64
    u16* leafbC   = (u16*)(ws + 187449344);
    u16* compbC   = (u16*)(ws + 187451392);
    u16* grevbC   = (u16*)(ws + 187453440);
    u16* decbC    = (u16*)(ws + 187455488);
    u16* clfbC    = (u16*)(ws + 187459584);
    u16* clfWC    = (u16*)(ws + 187459600);
    u32* flag     = (u32*)(ws + 187471888);

    detect_dtype<<<1, 256, 0, stream>>>((const u32*)wemb, flag);

    conv_sembP<<<32, 256, 0, stream>>>(semb, sembP, flag);
    conv_small<<<4,  256, 0, stream>>>(leafb, leafbC, 1024, flag);
    conv_small<<<4,  256, 0, stream>>>(compb, compbC, 1024, flag);
    conv_small<<<4,  256, 0, stream>>>(grevb, grevbC, 1024, flag);
    conv_small<<<8,  256, 0, stream>>>(decb,  decbC,  2048, flag);
    conv_small<<<1,  256, 0, stream>>>(clfb,  clfbC,  3,    flag);
    conv_small<<<24, 256, 0, stream>>>(clfW,  clfWC,  6144, flag);

    dim3 tb(32, 8);
    transpose_pad<<<dim3(32, 34), tb, 0, stream>>>(leafW, leafWt, 1024, 1088, flag,
        make_int4(0,0,0,0),      make_int4(0,0,0,0),       make_int4(1077,0,0,0));
    transpose_pad<<<dim3(32, 66), tb, 0, stream>>>(compW, compWt, 1024, 2112, flag,
        make_int4(0,64,1088,0),  make_int4(0,50,1074,0),   make_int4(50,1024,1024,0));
    transpose_pad<<<dim3(32, 34), tb, 0, stream>>>(grevW, grevWt, 1024, 1088, flag,
        make_int4(0,1024,0,0),   make_int4(0,1024,0,0),    make_int4(1024,50,0,0));
    transpose_pad<<<dim3(64, 68), tb, 0, stream>>>(decW,  decWt,  2048, 2176, flag,
        make_int4(0,64,128,1152), make_int4(0,50,100,1124), make_int4(50,50,1024,1024));

    // leaves -> up[511..1022]
    leaf_gather<<<16384, 256, 0, stream>>>(x, cue, pos, wemb, sembP, ctx, flag);
    gemm_fused<0,0><<<dim3(8, 128), 256, 0, stream>>>(leafWt, leafbC, up_buf,
        16384, 1088, 511, 9, 0, ctx, x, pos, sembP, up_buf, down_buf);
    // upward
    for (int lvl = 8; lvl >= 0; --lvl) {
        const int M = 32 << lvl;
        const int Mpad = M < 128 ? 128 : M;
        const int first = (1 << lvl) - 1;
        gemm_fused<1,1><<<dim3(8, Mpad >> 7), 256, 0, stream>>>(compWt, compbC, up_buf,
            M, 2112, first, lvl, 0, nullptr, x, pos, sembP, up_buf, down_buf);
    }
    // root -> down[0]
    gemm_fused<2,1><<<dim3(8, 1), 256, 0, stream>>>(grevWt, grevbC, down_buf,
        32, 1088, 0, 0, 0, nullptr, x, pos, sembP, up_buf, down_buf);
    // downward
    for (int lvl = 0; lvl <= 8; ++lvl) {
        const int M = 32 << lvl;
        const int Mpad = M < 128 ? 128 : M;
        const int first = (1 << lvl) - 1;
        gemm_fused<3,2><<<dim3(16, Mpad >> 7), 256, 0, stream>>>(decWt, decbC, down_buf,
            M, 2176, first, lvl, lvl == 8 ? 1 : 0, nullptr, x, pos, sembP, up_buf, down_buf);
    }
    // classifier
    classifier_kernel<<<1023, 256, 0, stream>>>(down_buf, up_buf, clfWC, clfbC, d_out, flag);
}

// Round 4
// 1290.092 us; speedup vs baseline: 1.3492x; 1.1009x over previous
//
#include <hip/hip_runtime.h>

typedef unsigned short u16;
typedef unsigned int   u32;

typedef __bf16 bf16x8 __attribute__((ext_vector_type(8)));
typedef float  f32x4  __attribute__((ext_vector_type(4)));

#define NB 1023   // nodes per tree
#define HH 1024   // hidden

__device__ __forceinline__ float b2f(u16 x) { return __uint_as_float(((u32)x) << 16); }
__device__ __forceinline__ u16 f2b(float f) {
    u32 u = __float_as_uint(f);
    u += 0x7fffu + ((u >> 16) & 1u);   // RTNE
    return (u16)(u >> 16);
}
__device__ __forceinline__ float fast_tanh(float x) {
    float cx = fminf(fmaxf(x, -12.f), 12.f);
    float e = __expf(2.f * cx);
    return __fdividef(e - 1.f, e + 1.f);
}
__device__ __forceinline__ void async_copy16(const void* gptr, void* lptr) {
    __builtin_amdgcn_global_load_lds((__attribute__((address_space(1))) void*)gptr,
                                     (__attribute__((address_space(3))) void*)lptr,
                                     16, 0, 0);
}
__device__ __forceinline__ u16 loadAsBf16(const void* p, size_t idx, int isf32) {
    if (isf32) return f2b(((const float*)p)[idx]);
    return ((const u16*)p)[idx];
}

// per-block dtype detection: f32 mantissa low-halves have random exponents.
// wemb[0..255] words are L2-hot after the first block touches them.
__device__ __forceinline__ int detect_local(const u32* __restrict__ w) {
    __shared__ int cnt;
    const int tid = threadIdx.x;
    if (tid == 0) cnt = 0;
    __syncthreads();
    u32 v = w[tid & 255];
    u32 lo = v & 0xFFFFu;
    u32 e = (lo >> 7) & 0xFFu;
    if ((lo != 0u) && (e < 60u || e > 140u)) atomicAdd(&cnt, 1);
    __syncthreads();
    return cnt >= 64;
}

// ---------------- unified preprocessing ----------------
__device__ void conv_range(const void* __restrict__ src, u16* __restrict__ dst,
                           int n, int tbase, int isf32) {
    const int i = ((int)blockIdx.x - tbase) * 256 + threadIdx.x;
    if (i < n) dst[i] = loadAsBf16(src, i, isf32);
}

__device__ void transpose_tile(const void* __restrict__ W, u16* __restrict__ Wt,
                               int Nw, int Kpad, int bx, int by, int isf32,
                               int ps0, int ps1, int ps2, int ps3,
                               int os0, int os1, int os2, int os3,
                               int ln0, int ln1, int ln2, int ln3)
{
    __shared__ u16 tile[32][33];
    const int tid = threadIdx.x;
    const int tx = tid & 31, ty = tid >> 5;
    #pragma unroll
    for (int i = 0; i < 4; ++i) {
        const int kp = by*32 + ty + i*8;
        const int n = bx*32 + tx;
        int ko = -1;
        if      (kp >= ps0 && kp < ps0 + ln0) ko = os0 + (kp - ps0);
        else if (kp >= ps1 && kp < ps1 + ln1) ko = os1 + (kp - ps1);
        else if (kp >= ps2 && kp < ps2 + ln2) ko = os2 + (kp - ps2);
        else if (kp >= ps3 && kp < ps3 + ln3) ko = os3 + (kp - ps3);
        u16 v = 0;
        if (ko >= 0) v = loadAsBf16(W, (size_t)ko * Nw + n, isf32);
        tile[ty + i*8][tx] = v;
    }
    __syncthreads();
    #pragma unroll
    for (int i = 0; i < 4; ++i) {
        const int n = bx*32 + ty + i*8;
        const int kp = by*32 + tx;
        Wt[(size_t)n * Kpad + kp] = tile[tx][ty + i*8];
    }
}

__global__ __launch_bounds__(256)
void preprocess(const u32* __restrict__ wembU,
                const void* __restrict__ semb,  const void* __restrict__ leafb,
                const void* __restrict__ compb, const void* __restrict__ grevb,
                const void* __restrict__ decb,  const void* __restrict__ clfb,
                const void* __restrict__ clfW,
                const void* __restrict__ leafW, const void* __restrict__ compW,
                const void* __restrict__ grevW, const void* __restrict__ decW,
                u16* __restrict__ sembP,  u16* __restrict__ leafbC,
                u16* __restrict__ compbC, u16* __restrict__ grevbC,
                u16* __restrict__ decbC,  u16* __restrict__ clfbC,
                u16* __restrict__ clfWC,
                u16* __restrict__ leafWt, u16* __restrict__ compWt,
                u16* __restrict__ grevWt, u16* __restrict__ decWt)
{
    const int isf32 = detect_local(wembU);
    const int bid = blockIdx.x;
    if (bid < 32) {                       // sembP: 128 rows, 50 -> 64 pad
        const int i = bid * 256 + threadIdx.x;   // 8192
        const int s = i >> 6, c = i & 63;
        sembP[i] = (c < 50) ? loadAsBf16(semb, s * 50 + c, isf32) : (u16)0;
    } else if (bid < 36)  conv_range(leafb, leafbC, 1024, 32, isf32);
    else if (bid < 40)  conv_range(compb, compbC, 1024, 36, isf32);
    else if (bid < 44)  conv_range(grevb, grevbC, 1024, 40, isf32);
    else if (bid < 52)  conv_range(decb,  decbC,  2048, 44, isf32);
    else if (bid < 53)  conv_range(clfb,  clfbC,  3,    52, isf32);
    else if (bid < 77)  conv_range(clfW,  clfWC,  6144, 53, isf32);
    else if (bid < 1165) {                // leafWt 32x34
        const int t = bid - 77;
        transpose_tile(leafW, leafWt, 1024, 1088, t & 31, t >> 5, isf32,
                       0,-1,-1,-1,  0,0,0,0,  1077,0,0,0);
    } else if (bid < 3277) {              // compWt 32x66
        const int t = bid - 1165;
        transpose_tile(compW, compWt, 1024, 2112, t & 31, t >> 5, isf32,
                       0,64,1088,-1,  0,50,1074,0,  50,1024,1024,0);
    } else if (bid < 4365) {              // grevWt 32x34
        const int t = bid - 3277;
        transpose_tile(grevW, grevWt, 1024, 1088, t & 31, t >> 5, isf32,
                       0,1024,-1,-1,  0,1024,0,0,  1024,50,0,0);
    } else {                              // decWt 64x68
        const int t = bid - 4365;
        transpose_tile(decW, decWt, 2048, 2176, t & 63, t >> 6, isf32,
                       0,64,128,1152,  0,50,100,1124,  50,50,1024,1024);
    }
}

// ---------------- leaf ctx (Kpad=1088): [word(1024) | onehot(3) | syn(pos)(50) | 0(11)]
__global__ __launch_bounds__(256)
void leaf_gather(const int* __restrict__ x, const int* __restrict__ cue,
                 const int* __restrict__ pos, const void* __restrict__ wemb,
                 const u16* __restrict__ sembP, u16* __restrict__ ctx)
{
    const int isf32 = detect_local((const u32*)wemb);
    const int m = blockIdx.x;           // 0..16383
    const int b = m >> 9, i = m & 511;
    const int node = 511 + i;
    const int s  = x[b*NB + node];
    const int cv = cue[b*NB + node];
    const int p  = pos[b*512 + i];
    u16* row = ctx + (size_t)m * 1088;
    u32* row32 = (u32*)row;
    const u16* sr = sembP + p * 64;
    const int tid = threadIdx.x;
    if (isf32) {
        const float2* wrf = ((const float2*)wemb) + (size_t)s * 512;
        for (int c = tid; c < 512; c += 256) {
            float2 t = wrf[c];
            row32[c] = (u32)f2b(t.x) | ((u32)f2b(t.y) << 16);
        }
    } else {
        const u32* wr = ((const u32*)wemb) + (size_t)s * 512;
        for (int c = tid; c < 512; c += 256) row32[c] = wr[c];
    }
    if (tid < 64) {
        const int c = tid;              // elem 1024+c
        u16 v;
        if (c < 3)       v = (c == cv) ? (u16)0x3F80 : (u16)0;
        else if (c < 53) v = sr[c - 3];
        else             v = 0;
        row[1024 + c] = v;
    }
}

// ---------------- fused gather+GEMM, BK=64 (two 32-chunks per barrier) ----------------
// C[M x N] = A[M x Kpad] * Bt[N x Kpad]^T + bias; A staged on the fly.
// AKIND 0: A = actx rows (leaf).             Kpad=1088
// AKIND 1: up level:   [semb(s)|up_l|up_r]   Kpad=2112 (64+1024+1024)
// AKIND 2: root:       [up0|semb(s)]         Kpad=1088 (1024+64)
// AKIND 3: down level: [sL|sR|down_n|up_n]   Kpad=2176 (64+64+1024+1024)
// MODE 0: store raw; 1: tanh; 2: tanh + child split (N=2048)
template<int AKIND, int MODE>
__global__ __launch_bounds__(256)
void gemm_fused(const u16* __restrict__ Bt, const u16* __restrict__ bias,
                u16* __restrict__ dst, int M, int Kpad, int nodeBase, int lognn,
                int leafLvl,
                const u16* __restrict__ actx,
                const int* __restrict__ x, const int* __restrict__ pos,
                const u16* __restrict__ sembP,
                const u16* __restrict__ upB, const u16* __restrict__ downB)
{
    __shared__ __align__(16) u16 As[2*4096];   // [chunk][128 rows x 32]
    __shared__ __align__(16) u16 Bs[2*4096];
    const int tid  = threadIdx.x;
    const int wave = tid >> 6;
    const int lane = tid & 63;
    const int bm = blockIdx.y << 7;
    const int bn = blockIdx.x << 7;
    const int wm = (wave & 1) << 6;
    const int wn = (wave >> 1) << 6;
    const int quad = lane >> 4;
    const int l16  = lane & 15;
    const int srow = lane >> 2;
    const int scol = (lane & 3) << 3;
    const int mask = (1 << lognn) - 1;

    // per-lane staging source pointers for its two A rows (mrow, mrow+64)
    const u16* p0[2]; const u16* p1[2]; const u16* p2[2]; const u16* p3[2];
    #pragma unroll
    for (int h = 0; h < 2; ++h) {
        const int mrow = bm + wave*16 + srow + h*64;
        // rows >= M stage harmless in-bounds data; their C rows are discarded
        const int mr = (mrow < M) ? mrow : 0;
        if (AKIND == 0) {
            p0[h] = actx + (size_t)mr * Kpad + scol;
        } else if (AKIND == 1) {
            const int b_ = mr >> lognn, ii = mr & mask;
            const int node = nodeBase + ii;
            const int s = x[b_*NB + node];
            p0[h] = sembP + s*64 + scol;
            p1[h] = upB + (((size_t)(b_*NB + 2*node + 1)) << 10) + scol;
            p2[h] = upB + (((size_t)(b_*NB + 2*node + 2)) << 10) + scol;
        } else if (AKIND == 2) {
            p0[h] = upB + (((size_t)(mr*NB)) << 10) + scol;
            p1[h] = sembP + x[mr*NB]*64 + scol;
        } else {
            const int b_ = mr >> lognn, ii = mr & mask;
            const int node = nodeBase + ii;
            const int l = 2*node + 1, r = l + 1;
            int sli, sri;
            if (leafLvl) { sli = pos[b_*512 + (l-511)]; sri = pos[b_*512 + (r-511)]; }
            else         { sli = x[b_*NB + l]; sri = x[b_*NB + r]; }
            p0[h] = sembP + sli*64 + scol;
            p1[h] = sembP + sri*64 + scol;
            p2[h] = downB + (((size_t)(b_*NB + node)) << 10) + scol;
            p3[h] = upB   + (((size_t)(b_*NB + node)) << 10) + scol;
        }
    }

    const u16* gB0 = Bt + (size_t)(bn + wave*16 + srow) * Kpad + scol;
    const u16* gB1 = gB0 + (size_t)64 * Kpad;
    u16* lA0 = &As[wave * 512];
    u16* lA1 = &As[(wave + 4) * 512];
    u16* lB0 = &Bs[wave * 512];
    u16* lB1 = &Bs[(wave + 4) * 512];

    const u16* pa[4]; const u16* pb[4];
    #pragma unroll
    for (int i = 0; i < 4; ++i) pa[i] = &As[(wm + i*16 + l16) * 32 + quad*8];
    #pragma unroll
    for (int j = 0; j < 4; ++j) pb[j] = &Bs[(wn + j*16 + l16) * 32 + quad*8];

    f32x4 zero4 = {0.f, 0.f, 0.f, 0.f};
    f32x4 acc[4][4];
    #pragma unroll
    for (int i = 0; i < 4; ++i)
        #pragma unroll
        for (int j = 0; j < 4; ++j) acc[i][j] = zero4;

    // one barrier per 64-wide K block (chunks at +0 and +32 from same segment)
    auto kstep64 = [&](const u16* sA0, const u16* sA1, int k0) {
        async_copy16(sA0,           lA0);
        async_copy16(sA1,           lA1);
        async_copy16(gB0 + k0,      lB0);
        async_copy16(gB1 + k0,      lB1);
        async_copy16(sA0 + 32,      lA0 + 4096);
        async_copy16(sA1 + 32,      lA1 + 4096);
        async_copy16(gB0 + k0 + 32, lB0 + 4096);
        async_copy16(gB1 + k0 + 32, lB1 + 4096);
        __syncthreads();
        #pragma unroll
        for (int c = 0; c < 2; ++c) {
            bf16x8 a[4], b[4];
            #pragma unroll
            for (int i = 0; i < 4; ++i) a[i] = *(const bf16x8*)(pa[i] + c*4096);
            #pragma unroll
            for (int j = 0; j < 4; ++j) b[j] = *(const bf16x8*)(pb[j] + c*4096);
            #pragma unroll
            for (int i = 0; i < 4; ++i)
                #pragma unroll
                for (int j = 0; j < 4; ++j)
                    acc[i][j] = __builtin_amdgcn_mfma_f32_16x16x32_bf16(a[i], b[j], acc[i][j], 0, 0, 0);
        }
        __syncthreads();
    };

    if (AKIND == 0) {
        for (int k0 = 0; k0 < 1088; k0 += 64) kstep64(p0[0] + k0, p0[1] + k0, k0);
    } else if (AKIND == 1) {
        kstep64(p0[0], p0[1], 0);
        for (int k0 = 64;   k0 < 1088; k0 += 64) kstep64(p1[0] + (k0-64),   p1[1] + (k0-64),   k0);
        for (int k0 = 1088; k0 < 2112; k0 += 64) kstep64(p2[0] + (k0-1088), p2[1] + (k0-1088), k0);
    } else if (AKIND == 2) {
        for (int k0 = 0; k0 < 1024; k0 += 64) kstep64(p0[0] + k0, p0[1] + k0, k0);
        kstep64(p1[0], p1[1], 1024);
    } else {
        kstep64(p0[0], p0[1], 0);
        kstep64(p1[0], p1[1], 64);
        for (int k0 = 128;  k0 < 1152; k0 += 64) kstep64(p2[0] + (k0-128),  p2[1] + (k0-128),  k0);
        for (int k0 = 1152; k0 < 2176; k0 += 64) kstep64(p3[0] + (k0-1152), p3[1] + (k0-1152), k0);
    }

    #pragma unroll
    for (int i = 0; i < 4; ++i) {
        #pragma unroll
        for (int j = 0; j < 4; ++j) {
            const int gn = bn + wn + j*16 + l16;
            const float bv = b2f(bias[gn]);
            #pragma unroll
            for (int r = 0; r < 4; ++r) {
                const int gm = bm + wm + i*16 + quad*4 + r;
                if (gm < M) {
                    float v = acc[i][j][r] + bv;
                    if (MODE != 0) v = fast_tanh(v);
                    const int b_ = gm >> lognn;
                    const int ii = gm & mask;
                    const int node = nodeBase + ii;
                    size_t addr;
                    if (MODE == 2) {
                        const int child = 2*node + 1 + (gn >> 10);
                        addr = (((size_t)(b_*NB + child)) << 10) + (gn & 1023);
                    } else {
                        addr = (((size_t)(b_*NB + node)) << 10) + gn;
                    }
                    dst[addr] = f2b(v);
                }
            }
        }
    }
}

// ---------------- classifier: out[b,n,c] = tanh([down|up] . clfW[:,c] + clfb[c]) ----
__global__ __launch_bounds__(256)
void classifier_kernel(const u16* __restrict__ down, const u16* __restrict__ up,
                       const u16* __restrict__ clfW, const u16* __restrict__ clfb,
                       void* __restrict__ outp, const u32* __restrict__ wembU)
{
    __shared__ float wls[3][2048];
    const int isf32 = detect_local(wembU);
    const int tid = threadIdx.x;
    for (int idx = tid; idx < 6144; idx += 256) {
        const int c = idx >> 11, k = idx & 2047;
        wls[c][k] = b2f(clfW[k*3 + c]);
    }
    __syncthreads();
    const int wave = tid >> 6, lane = tid & 63;
    const float b0 = b2f(clfb[0]), b1 = b2f(clfb[1]), b2v = b2f(clfb[2]);
    const int base = blockIdx.x * 32;
    for (int rr = 0; rr < 8; ++rr) {
        const int row = base + rr*4 + wave;     // row = b*NB + node
        const u32* dn = (const u32*)(down + ((size_t)row << 10));
        const u32* un = (const u32*)(up   + ((size_t)row << 10));
        float a0 = 0.f, a1 = 0.f, a2 = 0.f;
        #pragma unroll
        for (int t = 0; t < 8; ++t) {
            const int j = t*64 + lane;
            const u32 dp = dn[j], uu = un[j];
            const int k = j*2;
            const float d0 = __uint_as_float(dp << 16);
            const float d1 = __uint_as_float(dp & 0xffff0000u);
            const float u0 = __uint_as_float(uu << 16);
            const float u1 = __uint_as_float(uu & 0xffff0000u);
            a0 += d0*wls[0][k] + d1*wls[0][k+1] + u0*wls[0][1024+k] + u1*wls[0][1025+k];
            a1 += d0*wls[1][k] + d1*wls[1][k+1] + u0*wls[1][1024+k] + u1*wls[1][1025+k];
            a2 += d0*wls[2][k] + d1*wls[2][k+1] + u0*wls[2][1024+k] + u1*wls[2][1025+k];
        }
        #pragma unroll
        for (int off = 32; off; off >>= 1) {
            a0 += __shfl_down(a0, off);
            a1 += __shfl_down(a1, off);
            a2 += __shfl_down(a2, off);
        }
        if (lane == 0) {
            const float v0 = fast_tanh(a0 + b0);
            const float v1 = fast_tanh(a1 + b1);
            const float v2 = fast_tanh(a2 + b2v);
            if (isf32) {
                float* o = (float*)outp + (size_t)row * 3;
                o[0] = v0; o[1] = v1; o[2] = v2;
            } else {
                u16* o = (u16*)outp + (size_t)row * 3;
                o[0] = f2b(v0); o[1] = f2b(v1); o[2] = f2b(v2);
            }
        }
    }
}

extern "C" void kernel_launch(void* const* d_in, const int* in_sizes, int n_in,
                              void* d_out, int out_size, void* d_ws, size_t ws_size,
                              hipStream_t stream)
{
    (void)in_sizes; (void)n_in; (void)out_size; (void)ws_size;
    const int* x    = (const int*)d_in[0];
    const int* cue  = (const int*)d_in[2];
    const int* pos  = (const int*)d_in[4];
    const void* wemb  = d_in[6];
    const void* semb  = d_in[7];
    const void* leafW = d_in[8];
    const void* leafb = d_in[9];
    const void* compW = d_in[10];
    const void* compb = d_in[11];
    const void* grevW = d_in[12];
    const void* grevb = d_in[13];
    const void* decW  = d_in[14];
    const void* decb  = d_in[15];
    const void* clfW  = d_in[16];
    const void* clfb  = d_in[17];

    char* ws = (char*)d_ws;
    u16* up_buf   = (u16*)(ws + 0);            // 67043328
    u16* down_buf = (u16*)(ws + 67043328);     // 67043328
    u16* ctx      = (u16*)(ws + 134086656);    // 35651584 (leaf only)
    u16* leafWt   = (u16*)(ws + 169738240);    // 1024x1088
    u16* compWt   = (u16*)(ws + 171966464);    // 1024x2112
    u16* grevWt   = (u16*)(ws + 176291840);    // 1024x1088
    u16* decWt    = (u16*)(ws + 178520064);    // 2048x2176
    u16* sembP    = (u16*)(ws + 187432960);    // 128x64
    u16* leafbC   = (u16*)(ws + 187449344);
    u16* compbC   = (u16*)(ws + 187451392);
    u16* grevbC   = (u16*)(ws + 187453440);
    u16* decbC    = (u16*)(ws + 187455488);
    u16* clfbC    = (u16*)(ws + 187459584);
    u16* clfWC    = (u16*)(ws + 187459600);

    preprocess<<<8717, 256, 0, stream>>>((const u32*)wemb,
        semb, leafb, compb, grevb, decb, clfb, clfW,
        leafW, compW, grevW, decW,
        sembP, leafbC, compbC, grevbC, decbC, clfbC, clfWC,
        leafWt, compWt, grevWt, decWt);

    // leaves -> up[511..1022]
    leaf_gather<<<16384, 256, 0, stream>>>(x, cue, pos, wemb, sembP, ctx);
    gemm_fused<0,0><<<dim3(8, 128), 256, 0, stream>>>(leafWt, leafbC, up_buf,
        16384, 1088, 511, 9, 0, ctx, x, pos, sembP, up_buf, down_buf);
    // upward
    for (int lvl = 8; lvl >= 0; --lvl) {
        const int M = 32 << lvl;
        const int Mpad = M < 128 ? 128 : M;
        const int first = (1 << lvl) - 1;
        gemm_fused<1,1><<<dim3(8, Mpad >> 7), 256, 0, stream>>>(compWt, compbC, up_buf,
            M, 2112, first, lvl, 0, nullptr, x, pos, sembP, up_buf, down_buf);
    }
    // root -> down[0]
    gemm_fused<2,1><<<dim3(8, 1), 256, 0, stream>>>(grevWt, grevbC, down_buf,
        32, 1088, 0, 0, 0, nullptr, x, pos, sembP, up_buf, down_buf);
    // downward
    for (int lvl = 0; lvl <= 8; ++lvl) {
        const int M = 32 << lvl;
        const int Mpad = M < 128 ? 128 : M;
        const int first = (1 << lvl) - 1;
        gemm_fused<3,2><<<dim3(16, Mpad >> 7), 256, 0, stream>>>(decWt, decbC, down_buf,
            M, 2176, first, lvl, lvl == 8 ? 1 : 0, nullptr, x, pos, sembP, up_buf, down_buf);
    }
    // classifier
    classifier_kernel<<<1023, 256, 0, stream>>>(down_buf, up_buf, clfWC, clfbC,
                                                d_out, (const u32*)wemb);
}